// Round 1
// baseline (9189.949 us; speedup 1.0000x reference)
//
#include <hip/hip_runtime.h>
#include <hip/hip_bf16.h>
#include <cstdint>
#include <cstddef>

#define NEG_SLOPE 0.2f

// ---- monotone float<->uint mapping for atomicMax on floats ----
__device__ __forceinline__ unsigned fmap(float f) {
  unsigned u = __float_as_uint(f);
  return (u & 0x80000000u) ? ~u : (u | 0x80000000u);
}
__device__ __forceinline__ float funmap(unsigned v) {
  unsigned u = (v & 0x80000000u) ? (v ^ 0x80000000u) : ~v;
  return __uint_as_float(u);
}
// mapped value of -inf: ~0xFF800000 = 0x007FFFFF
#define MAPPED_NEG_INF 0x007FFFFFu

// ---------------- fills ----------------
__global__ void fill_f32(float* __restrict__ p, float v, long long n) {
  long long i = (long long)blockIdx.x * blockDim.x + threadIdx.x;
  long long s = (long long)gridDim.x * blockDim.x;
  for (; i < n; i += s) p[i] = v;
}
__global__ void fill_u32(unsigned* __restrict__ p, unsigned v, long long n) {
  long long i = (long long)blockIdx.x * blockDim.x + threadIdx.x;
  long long s = (long long)gridDim.x * blockDim.x;
  for (; i < n; i += s) p[i] = v;
}

// ---------------- simple per-node GEMM: Y[n,:] = X[n,:] @ W + b ----------------
// grid = N, block = OUT threads, dynamic LDS = K floats
__global__ void gemm_node(const float* __restrict__ X, const float* __restrict__ W,
                          const float* __restrict__ b, float* __restrict__ Y,
                          int K, int OUT) {
  extern __shared__ float xs[];
  const int n = blockIdx.x;
  for (int k = threadIdx.x; k < K; k += blockDim.x) xs[k] = X[(size_t)n * K + k];
  __syncthreads();
  const int j = threadIdx.x;
  if (j < OUT) {
    float acc = b[j];
    for (int k = 0; k < K; ++k) acc = fmaf(xs[k], W[(size_t)k * OUT + j], acc);
    Y[(size_t)n * OUT + j] = acc;
  }
}

// ---------------- layer 1 (H=4, C=64) edge kernels ----------------
__global__ void edge_score_l1(const float* __restrict__ xl, const float* __restrict__ xr,
                              const int* __restrict__ src, const int* __restrict__ dst,
                              const float* __restrict__ att, float* __restrict__ sc,
                              unsigned* __restrict__ m, int E) {
  __shared__ float4 As[64];  // att1: [4][64] = 64 float4
  if (threadIdx.x < 64) As[threadIdx.x] = ((const float4*)att)[threadIdx.x];
  __syncthreads();
  const int e = blockIdx.x * blockDim.x + threadIdx.x;
  if (e >= E) return;
  const int s = src[e], d = dst[e];
  const float4* pl = (const float4*)(xl + (size_t)s * 256);
  const float4* pr = (const float4*)(xr + (size_t)d * 256);
#pragma unroll
  for (int h = 0; h < 4; ++h) {
    float acc = 0.f;
#pragma unroll
    for (int q = 0; q < 16; ++q) {
      float4 a = pl[h * 16 + q], b = pr[h * 16 + q], w = As[h * 16 + q];
      float v;
      v = a.x + b.x; v = v > 0.f ? v : NEG_SLOPE * v; acc = fmaf(v, w.x, acc);
      v = a.y + b.y; v = v > 0.f ? v : NEG_SLOPE * v; acc = fmaf(v, w.y, acc);
      v = a.z + b.z; v = v > 0.f ? v : NEG_SLOPE * v; acc = fmaf(v, w.z, acc);
      v = a.w + b.w; v = v > 0.f ? v : NEG_SLOPE * v; acc = fmaf(v, w.w, acc);
    }
    sc[(size_t)e * 4 + h] = acc;
    atomicMax(&m[(size_t)d * 4 + h], fmap(acc));
  }
}

__global__ void edge_exp_l1(const int* __restrict__ dst, float* __restrict__ sc,
                            const unsigned* __restrict__ m, float* __restrict__ denom, int E) {
  const int e = blockIdx.x * blockDim.x + threadIdx.x;
  if (e >= E) return;
  const int d = dst[e];
  float4 s4 = ((const float4*)sc)[e];
  float a0 = expf(s4.x - funmap(m[(size_t)d * 4 + 0]));
  float a1 = expf(s4.y - funmap(m[(size_t)d * 4 + 1]));
  float a2 = expf(s4.z - funmap(m[(size_t)d * 4 + 2]));
  float a3 = expf(s4.w - funmap(m[(size_t)d * 4 + 3]));
  ((float4*)sc)[e] = make_float4(a0, a1, a2, a3);
  atomicAdd(&denom[(size_t)d * 4 + 0], a0);
  atomicAdd(&denom[(size_t)d * 4 + 1], a1);
  atomicAdd(&denom[(size_t)d * 4 + 2], a2);
  atomicAdd(&denom[(size_t)d * 4 + 3], a3);
}

// one 64-lane wave per edge; lane covers 4 consecutive floats of the 256-wide row
__global__ void scatter_l1(const float* __restrict__ xl, const int* __restrict__ src,
                           const int* __restrict__ dst, const float* __restrict__ sc,
                           const float* __restrict__ denom, float* __restrict__ out, int E) {
  long long t = (long long)blockIdx.x * blockDim.x + threadIdx.x;
  const int e = (int)(t >> 6);
  if (e >= E) return;
  const int lane = (int)(t & 63);
  const int s = src[e], d = dst[e];
  const int h = lane >> 4;
  const float alpha = sc[(size_t)e * 4 + h] / denom[(size_t)d * 4 + h];
  float4 v = *(const float4*)(xl + (size_t)s * 256 + lane * 4);
  float* op = out + (size_t)d * 256 + lane * 4;
  atomicAdd(op + 0, v.x * alpha);
  atomicAdd(op + 1, v.y * alpha);
  atomicAdd(op + 2, v.z * alpha);
  atomicAdd(op + 3, v.w * alpha);
}

// ---------------- layer 2 (H=1, C=64) edge kernels ----------------
__global__ void edge_score_l2(const float* __restrict__ xl, const float* __restrict__ xr,
                              const int* __restrict__ src, const int* __restrict__ dst,
                              const float* __restrict__ att, float* __restrict__ sc,
                              unsigned* __restrict__ m, int E) {
  __shared__ float4 As[16];  // att2: [1][64]
  if (threadIdx.x < 16) As[threadIdx.x] = ((const float4*)att)[threadIdx.x];
  __syncthreads();
  const int e = blockIdx.x * blockDim.x + threadIdx.x;
  if (e >= E) return;
  const int s = src[e], d = dst[e];
  const float4* pl = (const float4*)(xl + (size_t)s * 64);
  const float4* pr = (const float4*)(xr + (size_t)d * 64);
  float acc = 0.f;
#pragma unroll
  for (int q = 0; q < 16; ++q) {
    float4 a = pl[q], b = pr[q], w = As[q];
    float v;
    v = a.x + b.x; v = v > 0.f ? v : NEG_SLOPE * v; acc = fmaf(v, w.x, acc);
    v = a.y + b.y; v = v > 0.f ? v : NEG_SLOPE * v; acc = fmaf(v, w.y, acc);
    v = a.z + b.z; v = v > 0.f ? v : NEG_SLOPE * v; acc = fmaf(v, w.z, acc);
    v = a.w + b.w; v = v > 0.f ? v : NEG_SLOPE * v; acc = fmaf(v, w.w, acc);
  }
  sc[e] = acc;
  atomicMax(&m[d], fmap(acc));
}

__global__ void edge_exp_l2(const int* __restrict__ dst, float* __restrict__ sc,
                            const unsigned* __restrict__ m, float* __restrict__ denom, int E) {
  const int e = blockIdx.x * blockDim.x + threadIdx.x;
  if (e >= E) return;
  const int d = dst[e];
  float a = expf(sc[e] - funmap(m[d]));
  sc[e] = a;
  atomicAdd(&denom[d], a);
}

// 16 lanes per edge (64 floats per row)
__global__ void scatter_l2(const float* __restrict__ xl, const int* __restrict__ src,
                           const int* __restrict__ dst, const float* __restrict__ sc,
                           const float* __restrict__ denom, float* __restrict__ out, int E) {
  long long t = (long long)blockIdx.x * blockDim.x + threadIdx.x;
  const int e = (int)(t >> 4);
  if (e >= E) return;
  const int q = (int)(t & 15);
  const int s = src[e], d = dst[e];
  const float alpha = sc[e] / denom[d];
  float4 v = *(const float4*)(xl + (size_t)s * 64 + q * 4);
  float* op = out + (size_t)d * 64 + q * 4;
  atomicAdd(op + 0, v.x * alpha);
  atomicAdd(op + 1, v.y * alpha);
  atomicAdd(op + 2, v.z * alpha);
  atomicAdd(op + 3, v.w * alpha);
}

// ---------------- bias + ELU (in place) ----------------
__global__ void bias_elu(float* __restrict__ h, const float* __restrict__ bias,
                         long long n, int mask) {
  long long i = (long long)blockIdx.x * blockDim.x + threadIdx.x;
  long long s = (long long)gridDim.x * blockDim.x;
  for (; i < n; i += s) {
    float v = h[i] + bias[(int)(i & mask)];
    h[i] = v > 0.f ? v : expm1f(v);
  }
}

// ---------------- readout: out[n] = h2[n,:] @ Wro + bro (wave per node) ----------------
__global__ void readout(const float* __restrict__ h2, const float* __restrict__ Wro,
                        const float* __restrict__ bro, float* __restrict__ out, int N) {
  long long t = (long long)blockIdx.x * blockDim.x + threadIdx.x;
  const int n = (int)(t >> 6);
  if (n >= N) return;
  const int lane = (int)(t & 63);
  float v = h2[(size_t)n * 64 + lane] * Wro[lane];
#pragma unroll
  for (int off = 32; off > 0; off >>= 1) v += __shfl_down(v, off);
  if (lane == 0) out[n] = v + bro[0];
}

extern "C" void kernel_launch(void* const* d_in, const int* in_sizes, int n_in,
                              void* d_out, int out_size, void* d_ws, size_t ws_size,
                              hipStream_t stream) {
  const float* x     = (const float*)d_in[0];
  const int*   ei    = (const int*)d_in[1];
  const float* W1l   = (const float*)d_in[2];
  const float* b1l   = (const float*)d_in[3];
  const float* W1r   = (const float*)d_in[4];
  const float* b1r   = (const float*)d_in[5];
  const float* att1  = (const float*)d_in[6];
  const float* bias1 = (const float*)d_in[7];
  const float* W2l   = (const float*)d_in[8];
  const float* b2l   = (const float*)d_in[9];
  const float* W2r   = (const float*)d_in[10];
  const float* b2r   = (const float*)d_in[11];
  const float* att2  = (const float*)d_in[12];
  const float* bias2 = (const float*)d_in[13];
  const float* Wro   = (const float*)d_in[14];
  const float* bro   = (const float*)d_in[15];

  const int N = in_sizes[0] / 128;
  const int E = in_sizes[1] / 2;
  const int* src = ei;
  const int* dst = ei + E;

  // workspace layout (floats)
  float* ws  = (float*)d_ws;
  float* xl1 = ws;                          // N*256
  float* xr1 = xl1 + (size_t)N * 256;       // N*256
  float* h1  = xr1 + (size_t)N * 256;       // N*256 (acc -> elu'd h1; later reused as out2)
  float* sc1 = h1 + (size_t)N * 256;        // E*4
  unsigned* m1 = (unsigned*)(sc1 + (size_t)E * 4);  // N*4
  float* d1  = (float*)(m1 + (size_t)N * 4);        // N*4

  // -------- layer 1 --------
  gemm_node<<<dim3(N), dim3(256), 128 * sizeof(float), stream>>>(x, W1l, b1l, xl1, 128, 256);
  gemm_node<<<dim3(N), dim3(256), 128 * sizeof(float), stream>>>(x, W1r, b1r, xr1, 128, 256);
  fill_f32<<<dim3(2048), dim3(256), 0, stream>>>(h1, 0.f, (long long)N * 256);
  fill_u32<<<dim3(782), dim3(256), 0, stream>>>(m1, MAPPED_NEG_INF, (long long)N * 4);
  fill_f32<<<dim3(782), dim3(256), 0, stream>>>(d1, 0.f, (long long)N * 4);
  edge_score_l1<<<dim3((E + 255) / 256), dim3(256), 0, stream>>>(xl1, xr1, src, dst, att1, sc1, m1, E);
  edge_exp_l1<<<dim3((E + 255) / 256), dim3(256), 0, stream>>>(dst, sc1, m1, d1, E);
  {
    long long threads = (long long)E * 64;
    scatter_l1<<<dim3((unsigned)((threads + 255) / 256)), dim3(256), 0, stream>>>(
        xl1, src, dst, sc1, d1, h1, E);
  }
  bias_elu<<<dim3(2048), dim3(256), 0, stream>>>(h1, bias1, (long long)N * 256, 255);

  // -------- layer 2 (reuse buffers) --------
  float* xl2 = xl1;       // N*64
  float* xr2 = xr1;       // N*64
  float* sc2 = sc1;       // E
  unsigned* m2 = m1;      // N
  float* d2 = d1;         // N
  float* out2 = h1;       // N*64 (h1 dead after the two GEMMs below)

  gemm_node<<<dim3(N), dim3(64), 256 * sizeof(float), stream>>>(h1, W2l, b2l, xl2, 256, 64);
  gemm_node<<<dim3(N), dim3(64), 256 * sizeof(float), stream>>>(h1, W2r, b2r, xr2, 256, 64);
  fill_f32<<<dim3(2048), dim3(256), 0, stream>>>(out2, 0.f, (long long)N * 64);
  fill_u32<<<dim3(196), dim3(256), 0, stream>>>(m2, MAPPED_NEG_INF, (long long)N);
  fill_f32<<<dim3(196), dim3(256), 0, stream>>>(d2, 0.f, (long long)N);
  edge_score_l2<<<dim3((E + 255) / 256), dim3(256), 0, stream>>>(xl2, xr2, src, dst, att2, sc2, m2, E);
  edge_exp_l2<<<dim3((E + 255) / 256), dim3(256), 0, stream>>>(dst, sc2, m2, d2, E);
  {
    long long threads = (long long)E * 16;
    scatter_l2<<<dim3((unsigned)((threads + 255) / 256)), dim3(256), 0, stream>>>(
        xl2, src, dst, sc2, d2, out2, E);
  }
  bias_elu<<<dim3(2048), dim3(256), 0, stream>>>(out2, bias2, (long long)N * 64, 63);

  // -------- readout --------
  {
    long long threads = (long long)N * 64;
    readout<<<dim3((unsigned)((threads + 255) / 256)), dim3(256), 0, stream>>>(
        out2, Wro, bro, (float*)d_out, N);
  }
}

// Round 2
// 1773.811 us; speedup vs baseline: 5.1809x; 5.1809x over previous
//
#include <hip/hip_runtime.h>
#include <hip/hip_bf16.h>
#include <cstdint>
#include <cstddef>

#define NEG_SLOPE 0.2f

// ---------------- fills ----------------
__global__ void fill_u32(unsigned* __restrict__ p, unsigned v, long long n) {
  long long i = (long long)blockIdx.x * blockDim.x + threadIdx.x;
  long long s = (long long)gridDim.x * blockDim.x;
  for (; i < n; i += s) p[i] = v;
}

// ---------------- CSR build ----------------
__global__ void hist_dst(const int* __restrict__ dst, int* __restrict__ deg, int E) {
  int e = blockIdx.x * blockDim.x + threadIdx.x;
  if (e < E) atomicAdd(&deg[dst[e]], 1);
}

// single-block exclusive scan over deg[N] -> base[N], base[N]=E
__global__ void scan_deg(const int* __restrict__ deg, int* __restrict__ base, int N) {
  __shared__ int carry;
  __shared__ int tmp[1024];
  if (threadIdx.x == 0) carry = 0;
  __syncthreads();
  for (int start = 0; start < N; start += 1024) {
    int i = start + threadIdx.x;
    int v = (i < N) ? deg[i] : 0;
    tmp[threadIdx.x] = v;
    __syncthreads();
    for (int off = 1; off < 1024; off <<= 1) {
      int add = (threadIdx.x >= off) ? tmp[threadIdx.x - off] : 0;
      __syncthreads();
      tmp[threadIdx.x] += add;
      __syncthreads();
    }
    int incl = tmp[threadIdx.x];
    if (i < N) base[i] = carry + incl - v;  // exclusive
    __syncthreads();
    if (threadIdx.x == 0) carry += tmp[1023];
    __syncthreads();
  }
  if (threadIdx.x == 0) base[N] = carry;
}

__global__ void csr_build(const int* __restrict__ src, const int* __restrict__ dst,
                          const int* __restrict__ base, int* __restrict__ cursor,
                          int* __restrict__ csr_src, int* __restrict__ csr_dst, int E) {
  int e = blockIdx.x * blockDim.x + threadIdx.x;
  if (e >= E) return;
  int d = dst[e];
  int p = base[d] + atomicAdd(&cursor[d], 1);
  csr_src[p] = src[e];
  csr_dst[p] = d;
}

// ---------------- simple per-node GEMM: Y[n,:] = X[n,:] @ W + b ----------------
__global__ void gemm_node(const float* __restrict__ X, const float* __restrict__ W,
                          const float* __restrict__ b, float* __restrict__ Y,
                          int K, int OUT) {
  extern __shared__ float xs[];
  const int n = blockIdx.x;
  for (int k = threadIdx.x; k < K; k += blockDim.x) xs[k] = X[(size_t)n * K + k];
  __syncthreads();
  const int j = threadIdx.x;
  if (j < OUT) {
    float acc = b[j];
    for (int k = 0; k < K; ++k) acc = fmaf(xs[k], W[(size_t)k * OUT + j], acc);
    Y[(size_t)n * OUT + j] = acc;
  }
}

// ---------------- layer 1 scores (CSR order, H=4, C=64) ----------------
__global__ void score_l1(const float* __restrict__ xl, const float* __restrict__ xr,
                         const int* __restrict__ csr_src, const int* __restrict__ csr_dst,
                         const float* __restrict__ att, float* __restrict__ sc, int E) {
  __shared__ float4 As[64];  // att1: [4][64]
  if (threadIdx.x < 64) As[threadIdx.x] = ((const float4*)att)[threadIdx.x];
  __syncthreads();
  const int p = blockIdx.x * blockDim.x + threadIdx.x;
  if (p >= E) return;
  const int s = csr_src[p], d = csr_dst[p];
  const float4* pl = (const float4*)(xl + (size_t)s * 256);
  const float4* pr = (const float4*)(xr + (size_t)d * 256);
#pragma unroll
  for (int h = 0; h < 4; ++h) {
    float acc = 0.f;
#pragma unroll
    for (int q = 0; q < 16; ++q) {
      float4 a = pl[h * 16 + q], b = pr[h * 16 + q], w = As[h * 16 + q];
      float v;
      v = a.x + b.x; v = v > 0.f ? v : NEG_SLOPE * v; acc = fmaf(v, w.x, acc);
      v = a.y + b.y; v = v > 0.f ? v : NEG_SLOPE * v; acc = fmaf(v, w.y, acc);
      v = a.z + b.z; v = v > 0.f ? v : NEG_SLOPE * v; acc = fmaf(v, w.z, acc);
      v = a.w + b.w; v = v > 0.f ? v : NEG_SLOPE * v; acc = fmaf(v, w.w, acc);
    }
    sc[(size_t)p * 4 + h] = acc;
  }
}

// ---------------- layer 1 per-node softmax + gather + bias + ELU ----------------
// block = 256 threads: thread t -> (h = t>>6, c = t&63); wave w handles head w
// for the max/denom phases.
__global__ void node_l1(const float* __restrict__ xl, const int* __restrict__ csr_src,
                        const int* __restrict__ base, const float* __restrict__ sc,
                        const float* __restrict__ bias, float* __restrict__ out, int N) {
  const int n = blockIdx.x;
  const int t = threadIdx.x;
  const int wave = t >> 6, lane = t & 63;
  const int h = wave;
  const int beg = base[n], end = base[n + 1];
  const int deg = end - beg;

  __shared__ float mh[4], dh[4];
  __shared__ float al[64 * 4];
  __shared__ int ssrc[64];

  // phase 1: per-head max
  float mx = -INFINITY;
  for (int i = lane; i < deg; i += 64) mx = fmaxf(mx, sc[(size_t)(beg + i) * 4 + h]);
#pragma unroll
  for (int off = 32; off; off >>= 1) mx = fmaxf(mx, __shfl_xor(mx, off));
  if (lane == 0) mh[h] = mx;
  __syncthreads();

  // phase 2: per-head denom
  const float m = mh[h];
  float sm = 0.f;
  for (int i = lane; i < deg; i += 64) sm += __expf(sc[(size_t)(beg + i) * 4 + h] - m);
#pragma unroll
  for (int off = 32; off; off >>= 1) sm += __shfl_xor(sm, off);
  if (lane == 0) dh[h] = sm;
  __syncthreads();

  const float inv = 1.0f / dh[h];
  float acc = 0.f;
  for (int chunk = 0; chunk < deg; chunk += 64) {
    const int cnt = min(64, deg - chunk);
    __syncthreads();
    if (t < cnt) ssrc[t] = csr_src[beg + chunk + t];
    if (t < cnt * 4) {
      const int i = t >> 2, hh = t & 3;
      al[t] = __expf(sc[(size_t)(beg + chunk + i) * 4 + hh] - mh[hh]) * (1.0f / dh[hh]);
    }
    __syncthreads();
    for (int i = 0; i < cnt; ++i) {
      acc = fmaf(al[i * 4 + h], xl[(size_t)ssrc[i] * 256 + t], acc);
    }
  }
  (void)inv;
  float v = acc + bias[t];
  out[(size_t)n * 256 + t] = v > 0.f ? v : expm1f(v);
}

// ---------------- layer 2 scores (CSR order, H=1, C=64) ----------------
__global__ void score_l2(const float* __restrict__ xl, const float* __restrict__ xr,
                         const int* __restrict__ csr_src, const int* __restrict__ csr_dst,
                         const float* __restrict__ att, float* __restrict__ sc, int E) {
  __shared__ float4 As[16];
  if (threadIdx.x < 16) As[threadIdx.x] = ((const float4*)att)[threadIdx.x];
  __syncthreads();
  const int p = blockIdx.x * blockDim.x + threadIdx.x;
  if (p >= E) return;
  const int s = csr_src[p], d = csr_dst[p];
  const float4* pl = (const float4*)(xl + (size_t)s * 64);
  const float4* pr = (const float4*)(xr + (size_t)d * 64);
  float acc = 0.f;
#pragma unroll
  for (int q = 0; q < 16; ++q) {
    float4 a = pl[q], b = pr[q], w = As[q];
    float v;
    v = a.x + b.x; v = v > 0.f ? v : NEG_SLOPE * v; acc = fmaf(v, w.x, acc);
    v = a.y + b.y; v = v > 0.f ? v : NEG_SLOPE * v; acc = fmaf(v, w.y, acc);
    v = a.z + b.z; v = v > 0.f ? v : NEG_SLOPE * v; acc = fmaf(v, w.z, acc);
    v = a.w + b.w; v = v > 0.f ? v : NEG_SLOPE * v; acc = fmaf(v, w.w, acc);
  }
  sc[p] = acc;
}

// ---------------- layer 2 per-node + bias + ELU + readout (fused) ----------------
// block = 256 = 4 waves; wave handles node blockIdx.x*4 + wave; lane = channel.
__global__ void node_l2(const float* __restrict__ xl, const int* __restrict__ csr_src,
                        const int* __restrict__ base, const float* __restrict__ sc,
                        const float* __restrict__ bias, const float* __restrict__ Wro,
                        const float* __restrict__ bro, float* __restrict__ out, int N) {
  const int wave = threadIdx.x >> 6, lane = threadIdx.x & 63;
  const int n = blockIdx.x * 4 + wave;
  if (n >= N) return;
  const int beg = base[n], end = base[n + 1];
  const int deg = end - beg;

  float mx = -INFINITY;
  for (int i = lane; i < deg; i += 64) mx = fmaxf(mx, sc[beg + i]);
#pragma unroll
  for (int off = 32; off; off >>= 1) mx = fmaxf(mx, __shfl_xor(mx, off));

  float sm = 0.f;
  for (int i = lane; i < deg; i += 64) sm += __expf(sc[beg + i] - mx);
#pragma unroll
  for (int off = 32; off; off >>= 1) sm += __shfl_xor(sm, off);
  const float inv = 1.0f / sm;

  float acc = 0.f;
  for (int i = 0; i < deg; ++i) {
    const int s = csr_src[beg + i];              // broadcast
    const float a = __expf(sc[beg + i] - mx) * inv;
    acc = fmaf(a, xl[(size_t)s * 64 + lane], acc);
  }

  float v = acc + bias[lane];
  v = v > 0.f ? v : expm1f(v);
  float r = v * Wro[lane];
#pragma unroll
  for (int off = 32; off; off >>= 1) r += __shfl_xor(r, off);
  if (lane == 0) out[n] = r + bro[0];
}

extern "C" void kernel_launch(void* const* d_in, const int* in_sizes, int n_in,
                              void* d_out, int out_size, void* d_ws, size_t ws_size,
                              hipStream_t stream) {
  const float* x     = (const float*)d_in[0];
  const int*   ei    = (const int*)d_in[1];
  const float* W1l   = (const float*)d_in[2];
  const float* b1l   = (const float*)d_in[3];
  const float* W1r   = (const float*)d_in[4];
  const float* b1r   = (const float*)d_in[5];
  const float* att1  = (const float*)d_in[6];
  const float* bias1 = (const float*)d_in[7];
  const float* W2l   = (const float*)d_in[8];
  const float* b2l   = (const float*)d_in[9];
  const float* W2r   = (const float*)d_in[10];
  const float* b2r   = (const float*)d_in[11];
  const float* att2  = (const float*)d_in[12];
  const float* bias2 = (const float*)d_in[13];
  const float* Wro   = (const float*)d_in[14];
  const float* bro   = (const float*)d_in[15];

  const int N = in_sizes[0] / 128;
  const int E = in_sizes[1] / 2;
  const int* src = ei;
  const int* dst = ei + E;

  // ---- workspace layout ----
  float* A   = (float*)d_ws;                    // xl1 [N*256]; later xl2/xr2 [N*64 each]
  float* B   = A + (size_t)N * 256;             // xr1 [N*256]; later h1 [N*256]
  float* C   = B + (size_t)N * 256;             // sc1 [E*4]; later sc2 [E]
  int* csr_src = (int*)(C + (size_t)E * 4);     // [E]
  int* csr_dst = csr_src + E;                   // [E]
  int* deg     = csr_dst + E;                   // [N]
  int* base    = deg + N;                       // [N+1]
  int* cursor  = base + N + 1;                  // [N]

  const int EB = (E + 255) / 256;

  // ---- CSR build (shared by both layers) ----
  fill_u32<<<dim3(98), dim3(256), 0, stream>>>((unsigned*)deg, 0u, N);
  fill_u32<<<dim3(98), dim3(256), 0, stream>>>((unsigned*)cursor, 0u, N);
  hist_dst<<<dim3(EB), dim3(256), 0, stream>>>(dst, deg, E);
  scan_deg<<<dim3(1), dim3(1024), 0, stream>>>(deg, base, N);
  csr_build<<<dim3(EB), dim3(256), 0, stream>>>(src, dst, base, cursor, csr_src, csr_dst, E);

  // ---- layer 1 ----
  float* xl1 = A;
  float* xr1 = B;
  gemm_node<<<dim3(N), dim3(256), 128 * sizeof(float), stream>>>(x, W1l, b1l, xl1, 128, 256);
  gemm_node<<<dim3(N), dim3(256), 128 * sizeof(float), stream>>>(x, W1r, b1r, xr1, 128, 256);
  score_l1<<<dim3(EB), dim3(256), 0, stream>>>(xl1, xr1, csr_src, csr_dst, att1, C, E);
  float* h1 = B;  // overwrites xr1 (dead after score_l1); node_l1 reads only xl1 + sc
  node_l1<<<dim3(N), dim3(256), 0, stream>>>(xl1, csr_src, base, C, bias1, h1, N);

  // ---- layer 2 ----
  float* xl2 = A;                 // xl1 dead
  float* xr2 = A + (size_t)N * 64;
  gemm_node<<<dim3(N), dim3(64), 256 * sizeof(float), stream>>>(h1, W2l, b2l, xl2, 256, 64);
  gemm_node<<<dim3(N), dim3(64), 256 * sizeof(float), stream>>>(h1, W2r, b2r, xr2, 256, 64);
  score_l2<<<dim3(EB), dim3(256), 0, stream>>>(xl2, xr2, csr_src, csr_dst, att2, C, E);
  node_l2<<<dim3((N + 3) / 4), dim3(256), 0, stream>>>(xl2, csr_src, base, C, bias2, Wro, bro,
                                                       (float*)d_out, N);
}

// Round 3
// 1095.931 us; speedup vs baseline: 8.3855x; 1.6185x over previous
//
#include <hip/hip_runtime.h>
#include <hip/hip_bf16.h>
#include <cstdint>
#include <cstddef>

#define NEG_SLOPE 0.2f

// ---------------- fills ----------------
__global__ void fill_u32(unsigned* __restrict__ p, unsigned v, long long n) {
  long long i = (long long)blockIdx.x * blockDim.x + threadIdx.x;
  long long s = (long long)gridDim.x * blockDim.x;
  for (; i < n; i += s) p[i] = v;
}

// ---------------- CSR build ----------------
__global__ void hist_dst(const int* __restrict__ dst, int* __restrict__ deg, int E) {
  int e = blockIdx.x * blockDim.x + threadIdx.x;
  if (e < E) atomicAdd(&deg[dst[e]], 1);
}

// scan kernel 1: per-256-block inclusive scan of deg -> base, block sums -> bsum
__global__ void scan1(const int* __restrict__ deg, int* __restrict__ base,
                      int* __restrict__ bsum, int N) {
  const int t = threadIdx.x;
  const int i = blockIdx.x * 256 + t;
  const int lane = t & 63, w = t >> 6;
  int v = (i < N) ? deg[i] : 0;
  int x = v;
#pragma unroll
  for (int off = 1; off < 64; off <<= 1) {
    int y = __shfl_up(x, off);
    if (lane >= off) x += y;
  }
  __shared__ int wsum[4];
  if (lane == 63) wsum[w] = x;
  __syncthreads();
  int add = 0;
  for (int j = 0; j < w; ++j) add += wsum[j];
  x += add;
  if (i < N) base[i] = x;  // inclusive for now
  if (t == 255) bsum[blockIdx.x] = x;
}

// scan kernel 2: exclusive scan of bsum[nb] (nb <= 256), single block
__global__ void scan2(int* __restrict__ bsum, int* __restrict__ boff, int nb) {
  const int t = threadIdx.x;
  const int lane = t & 63, w = t >> 6;
  int v = (t < nb) ? bsum[t] : 0;
  int x = v;
#pragma unroll
  for (int off = 1; off < 64; off <<= 1) {
    int y = __shfl_up(x, off);
    if (lane >= off) x += y;
  }
  __shared__ int wsum[4];
  if (lane == 63) wsum[w] = x;
  __syncthreads();
  int add = 0;
  for (int j = 0; j < w; ++j) add += wsum[j];
  x += add;
  if (t < nb) boff[t] = x - v;  // exclusive
}

// scan kernel 3: finalize exclusive base; base[N] = E
__global__ void scan3(int* __restrict__ base, const int* __restrict__ deg,
                      const int* __restrict__ boff, int N, int E) {
  const int i = blockIdx.x * blockDim.x + threadIdx.x;
  if (i < N) base[i] = base[i] - deg[i] + boff[i >> 8];
  else if (i == N) base[N] = E;
}

__global__ void csr_build(const int* __restrict__ src, const int* __restrict__ dst,
                          const int* __restrict__ base, int* __restrict__ cursor,
                          int* __restrict__ csr_src, int E) {
  int e = blockIdx.x * blockDim.x + threadIdx.x;
  if (e >= E) return;
  int d = dst[e];
  int p = base[d] + atomicAdd(&cursor[d], 1);
  csr_src[p] = src[e];
}

// ---------------- batched GEMM, layer 1: [N,128] @ [128,256] + b ----------------
// block 256 thr, 8 nodes/block; thread t computes column t for all 8 rows
__global__ void gemm_l1(const float* __restrict__ X, const float* __restrict__ W,
                        const float* __restrict__ b, float* __restrict__ Y, int N) {
  __shared__ float xs[8 * 128];
  const int t = threadIdx.x;
  const int n0 = blockIdx.x * 8;
#pragma unroll
  for (int q = 0; q < 4; ++q) xs[t + q * 256] = X[(size_t)n0 * 128 + t + q * 256];
  __syncthreads();
  float acc[8];
  const float bj = b[t];
#pragma unroll
  for (int r = 0; r < 8; ++r) acc[r] = bj;
#pragma unroll 4
  for (int k = 0; k < 128; ++k) {
    const float w = W[(size_t)k * 256 + t];
#pragma unroll
    for (int r = 0; r < 8; ++r) acc[r] = fmaf(xs[r * 128 + k], w, acc[r]);
  }
#pragma unroll
  for (int r = 0; r < 8; ++r) Y[(size_t)(n0 + r) * 256 + t] = acc[r];
}

// ---------------- batched GEMM, layer 2: [N,256] @ [256,64] + b ----------------
// block 256 thr, 16 nodes/block; thread t: j=t&63, rows (t>>6)*4..+3
__global__ void gemm_l2(const float* __restrict__ X, const float* __restrict__ W,
                        const float* __restrict__ b, float* __restrict__ Y, int N) {
  __shared__ float xs[16 * 256];
  const int t = threadIdx.x;
  const int n0 = blockIdx.x * 16;
#pragma unroll
  for (int q = 0; q < 16; ++q) xs[t + q * 256] = X[(size_t)n0 * 256 + t + q * 256];
  __syncthreads();
  const int j = t & 63;
  const int r0 = (t >> 6) * 4;
  float acc[4];
  const float bj = b[j];
#pragma unroll
  for (int q = 0; q < 4; ++q) acc[q] = bj;
#pragma unroll 4
  for (int k = 0; k < 256; ++k) {
    const float w = W[(size_t)k * 64 + j];
#pragma unroll
    for (int q = 0; q < 4; ++q) acc[q] = fmaf(xs[(r0 + q) * 256 + k], w, acc[q]);
  }
#pragma unroll
  for (int q = 0; q < 4; ++q) Y[(size_t)(n0 + r0 + q) * 64 + j] = acc[q];
}

// ---------------- layer 1 fused: online softmax + aggregate + bias + ELU ----------------
// block 256 = 4 waves; wave w handles head w (channels = lanes); node = blockIdx.x
__global__ void node_l1_fused(const float* __restrict__ xl, const float* __restrict__ xr,
                              const int* __restrict__ csr_src, const int* __restrict__ base,
                              const float* __restrict__ att, const float* __restrict__ bias,
                              float* __restrict__ out, int N) {
  const int n = blockIdx.x;
  const int t = threadIdx.x;
  const int beg = base[n];
  const int deg = base[n + 1] - beg;
  const float xrv = xr[(size_t)n * 256 + t];
  const float attv = att[t];

  float m = -INFINITY, dsum = 0.f, acc = 0.f;

  // software-pipelined gather: one xl row in flight
  float xlv_next = 0.f;
  if (deg > 0) {
    const int s0 = csr_src[beg];
    xlv_next = xl[(size_t)s0 * 256 + t];
  }
  for (int i = 0; i < deg; ++i) {
    const float xlv = xlv_next;
    if (i + 1 < deg) {
      const int s = csr_src[beg + i + 1];
      xlv_next = xl[(size_t)s * 256 + t];
    }
    float v = xlv + xrv;
    v = v > 0.f ? v : NEG_SLOPE * v;
    float sc = v * attv;
#pragma unroll
    for (int off = 32; off; off >>= 1) sc += __shfl_xor(sc, off);
    const float mnew = fmaxf(m, sc);
    const float scale = __expf(m - mnew);
    const float p = __expf(sc - mnew);
    dsum = dsum * scale + p;
    acc = acc * scale + p * xlv;
    m = mnew;
  }
  float o = (deg > 0) ? acc / dsum : 0.f;
  o += bias[t];
  out[(size_t)n * 256 + t] = o > 0.f ? o : expm1f(o);
}

// ---------------- layer 2 fused: + readout ----------------
// 4 waves/block; wave handles node blockIdx.x*4+wave; lane = channel
__global__ void node_l2_fused(const float* __restrict__ xl, const float* __restrict__ xr,
                              const int* __restrict__ csr_src, const int* __restrict__ base,
                              const float* __restrict__ att, const float* __restrict__ bias,
                              const float* __restrict__ Wro, const float* __restrict__ bro,
                              float* __restrict__ out, int N) {
  const int wave = threadIdx.x >> 6, lane = threadIdx.x & 63;
  const int n = blockIdx.x * 4 + wave;
  if (n >= N) return;
  const int beg = base[n];
  const int deg = base[n + 1] - beg;
  const float xrv = xr[(size_t)n * 64 + lane];
  const float attv = att[lane];

  float m = -INFINITY, dsum = 0.f, acc = 0.f;
  float xlv_next = 0.f;
  if (deg > 0) {
    const int s0 = csr_src[beg];
    xlv_next = xl[(size_t)s0 * 64 + lane];
  }
  for (int i = 0; i < deg; ++i) {
    const float xlv = xlv_next;
    if (i + 1 < deg) {
      const int s = csr_src[beg + i + 1];
      xlv_next = xl[(size_t)s * 64 + lane];
    }
    float v = xlv + xrv;
    v = v > 0.f ? v : NEG_SLOPE * v;
    float sc = v * attv;
#pragma unroll
    for (int off = 32; off; off >>= 1) sc += __shfl_xor(sc, off);
    const float mnew = fmaxf(m, sc);
    const float scale = __expf(m - mnew);
    const float p = __expf(sc - mnew);
    dsum = dsum * scale + p;
    acc = acc * scale + p * xlv;
    m = mnew;
  }
  float o = (deg > 0) ? acc / dsum : 0.f;
  o += bias[lane];
  o = o > 0.f ? o : expm1f(o);
  float r = o * Wro[lane];
#pragma unroll
  for (int off = 32; off; off >>= 1) r += __shfl_xor(r, off);
  if (lane == 0) out[n] = r + bro[0];
}

extern "C" void kernel_launch(void* const* d_in, const int* in_sizes, int n_in,
                              void* d_out, int out_size, void* d_ws, size_t ws_size,
                              hipStream_t stream) {
  const float* x     = (const float*)d_in[0];
  const int*   ei    = (const int*)d_in[1];
  const float* W1l   = (const float*)d_in[2];
  const float* b1l   = (const float*)d_in[3];
  const float* W1r   = (const float*)d_in[4];
  const float* b1r   = (const float*)d_in[5];
  const float* att1  = (const float*)d_in[6];
  const float* bias1 = (const float*)d_in[7];
  const float* W2l   = (const float*)d_in[8];
  const float* b2l   = (const float*)d_in[9];
  const float* W2r   = (const float*)d_in[10];
  const float* b2r   = (const float*)d_in[11];
  const float* att2  = (const float*)d_in[12];
  const float* bias2 = (const float*)d_in[13];
  const float* Wro   = (const float*)d_in[14];
  const float* bro   = (const float*)d_in[15];

  const int N = in_sizes[0] / 128;
  const int E = in_sizes[1] / 2;
  const int* src = ei;
  const int* dst = ei + E;

  // ---- workspace layout (floats) ----
  float* A    = (float*)d_ws;                 // xl1 [N*256]; later xl2/xr2 [N*64 each]
  float* B    = A + (size_t)N * 256;          // xr1 [N*256]
  float* Hbuf = B + (size_t)N * 256;          // h1 [N*256]
  int* csr_src = (int*)(Hbuf + (size_t)N * 256);  // [E]
  int* deg     = csr_src + E;                 // [N]
  int* base    = deg + N;                     // [N+1]
  int* cursor  = base + N + 1;                // [N]
  int* bsum    = cursor + N;                  // [256]
  int* boff    = bsum + 256;                  // [256]

  const int EB = (E + 255) / 256;             // 6250
  const int NB = (N + 255) / 256;             // 196

  // ---- CSR build ----
  fill_u32<<<dim3(98), dim3(256), 0, stream>>>((unsigned*)deg, 0u, N);
  fill_u32<<<dim3(98), dim3(256), 0, stream>>>((unsigned*)cursor, 0u, N);
  hist_dst<<<dim3(EB), dim3(256), 0, stream>>>(dst, deg, E);
  scan1<<<dim3(NB), dim3(256), 0, stream>>>(deg, base, bsum, N);
  scan2<<<dim3(1), dim3(256), 0, stream>>>(bsum, boff, NB);
  scan3<<<dim3(NB + 1), dim3(256), 0, stream>>>(base, deg, boff, N, E);
  csr_build<<<dim3(EB), dim3(256), 0, stream>>>(src, dst, base, cursor, csr_src, E);

  // ---- layer 1 ----
  float* xl1 = A;
  float* xr1 = B;
  gemm_l1<<<dim3(N / 8), dim3(256), 0, stream>>>(x, W1l, b1l, xl1, N);
  gemm_l1<<<dim3(N / 8), dim3(256), 0, stream>>>(x, W1r, b1r, xr1, N);
  node_l1_fused<<<dim3(N), dim3(256), 0, stream>>>(xl1, xr1, csr_src, base, att1, bias1,
                                                   Hbuf, N);

  // ---- layer 2 (xl1/xr1 dead) ----
  float* xl2 = A;
  float* xr2 = A + (size_t)N * 64;
  gemm_l2<<<dim3(N / 16), dim3(256), 0, stream>>>(Hbuf, W2l, b2l, xl2, N);
  gemm_l2<<<dim3(N / 16), dim3(256), 0, stream>>>(Hbuf, W2r, b2r, xr2, N);
  node_l2_fused<<<dim3((N + 3) / 4), dim3(256), 0, stream>>>(xl2, xr2, csr_src, base, att2,
                                                             bias2, Wro, bro, (float*)d_out, N);
}

// Round 4
// 692.281 us; speedup vs baseline: 13.2749x; 1.5831x over previous
//
#include <hip/hip_runtime.h>
#include <hip/hip_bf16.h>
#include <cstdint>
#include <cstddef>

#define NEG_SLOPE 0.2f

__device__ __forceinline__ float lrelu(float v) { return v > 0.f ? v : NEG_SLOPE * v; }

// ---------------- fills ----------------
__global__ void fill_u32(unsigned* __restrict__ p, unsigned v, long long n) {
  long long i = (long long)blockIdx.x * blockDim.x + threadIdx.x;
  long long s = (long long)gridDim.x * blockDim.x;
  for (; i < n; i += s) p[i] = v;
}

// ---------------- CSR build ----------------
__global__ void hist_dst(const int* __restrict__ dst, int* __restrict__ deg, int E) {
  int e = blockIdx.x * blockDim.x + threadIdx.x;
  if (e < E) atomicAdd(&deg[dst[e]], 1);
}

__global__ void scan1(const int* __restrict__ deg, int* __restrict__ base,
                      int* __restrict__ bsum, int N) {
  const int t = threadIdx.x;
  const int i = blockIdx.x * 256 + t;
  const int lane = t & 63, w = t >> 6;
  int v = (i < N) ? deg[i] : 0;
  int x = v;
#pragma unroll
  for (int off = 1; off < 64; off <<= 1) {
    int y = __shfl_up(x, off);
    if (lane >= off) x += y;
  }
  __shared__ int wsum[4];
  if (lane == 63) wsum[w] = x;
  __syncthreads();
  int add = 0;
  for (int j = 0; j < w; ++j) add += wsum[j];
  x += add;
  if (i < N) base[i] = x;  // inclusive for now
  if (t == 255) bsum[blockIdx.x] = x;
}

__global__ void scan2(int* __restrict__ bsum, int* __restrict__ boff, int nb) {
  const int t = threadIdx.x;
  const int lane = t & 63, w = t >> 6;
  int v = (t < nb) ? bsum[t] : 0;
  int x = v;
#pragma unroll
  for (int off = 1; off < 64; off <<= 1) {
    int y = __shfl_up(x, off);
    if (lane >= off) x += y;
  }
  __shared__ int wsum[4];
  if (lane == 63) wsum[w] = x;
  __syncthreads();
  int add = 0;
  for (int j = 0; j < w; ++j) add += wsum[j];
  x += add;
  if (t < nb) boff[t] = x - v;  // exclusive
}

__global__ void scan3(int* __restrict__ base, const int* __restrict__ deg,
                      const int* __restrict__ boff, int N, int E) {
  const int i = blockIdx.x * blockDim.x + threadIdx.x;
  if (i < N) base[i] = base[i] - deg[i] + boff[i >> 8];
  else if (i == N) base[N] = E;
}

__global__ void csr_build(const int* __restrict__ src, const int* __restrict__ dst,
                          const int* __restrict__ base, int* __restrict__ cursor,
                          int* __restrict__ csr_src, int E) {
  int e = blockIdx.x * blockDim.x + threadIdx.x;
  if (e >= E) return;
  int d = dst[e];
  int p = base[d] + atomicAdd(&cursor[d], 1);
  csr_src[p] = src[e];
}

// ---------------- batched GEMM, layer 1: [N,128] @ [128,256] + b ----------------
__global__ void gemm_l1(const float* __restrict__ X, const float* __restrict__ W,
                        const float* __restrict__ b, float* __restrict__ Y, int N) {
  __shared__ float xs[8 * 128];
  const int t = threadIdx.x;
  const int n0 = blockIdx.x * 8;
#pragma unroll
  for (int q = 0; q < 4; ++q) xs[t + q * 256] = X[(size_t)n0 * 128 + t + q * 256];
  __syncthreads();
  float acc[8];
  const float bj = b[t];
#pragma unroll
  for (int r = 0; r < 8; ++r) acc[r] = bj;
#pragma unroll 4
  for (int k = 0; k < 128; ++k) {
    const float w = W[(size_t)k * 256 + t];
#pragma unroll
    for (int r = 0; r < 8; ++r) acc[r] = fmaf(xs[r * 128 + k], w, acc[r]);
  }
#pragma unroll
  for (int r = 0; r < 8; ++r) Y[(size_t)(n0 + r) * 256 + t] = acc[r];
}

// ---------------- batched GEMM, layer 2: [N,256] @ [256,64] + b ----------------
__global__ void gemm_l2(const float* __restrict__ X, const float* __restrict__ W,
                        const float* __restrict__ b, float* __restrict__ Y, int N) {
  __shared__ float xs[16 * 256];
  const int t = threadIdx.x;
  const int n0 = blockIdx.x * 16;
#pragma unroll
  for (int q = 0; q < 16; ++q) xs[t + q * 256] = X[(size_t)n0 * 256 + t + q * 256];
  __syncthreads();
  const int j = t & 63;
  const int r0 = (t >> 6) * 4;
  float acc[4];
  const float bj = b[j];
#pragma unroll
  for (int q = 0; q < 4; ++q) acc[q] = bj;
#pragma unroll 4
  for (int k = 0; k < 256; ++k) {
    const float w = W[(size_t)k * 64 + j];
#pragma unroll
    for (int q = 0; q < 4; ++q) acc[q] = fmaf(xs[(r0 + q) * 256 + k], w, acc[q]);
  }
#pragma unroll
  for (int q = 0; q < 4; ++q) Y[(size_t)(n0 + r0 + q) * 64 + j] = acc[q];
}

// ---------------- layer 1 fused: wave per node, float4 per lane ----------------
// lane l owns channels [4l, 4l+4); head = l>>4; score reduce over 16 lanes.
__global__ __launch_bounds__(256) void node_l1_fused(
    const float* __restrict__ xl, const float* __restrict__ xr,
    const int* __restrict__ csr_src, const int* __restrict__ base,
    const float* __restrict__ att, const float* __restrict__ bias,
    float* __restrict__ out, int N) {
  const int wv = threadIdx.x >> 6, lane = threadIdx.x & 63;
  const int n = blockIdx.x * 4 + wv;
  if (n >= N) return;
  const int beg = base[n];
  const int deg = base[n + 1] - beg;
  const float4 xrv = ((const float4*)xr)[(size_t)n * 64 + lane];
  const float4 attv = ((const float4*)att)[lane];

  float m = -INFINITY, dsum = 0.f;
  float4 acc = make_float4(0.f, 0.f, 0.f, 0.f);

  for (int chunk = 0; chunk < deg; chunk += 64) {
    const int cnt = min(64, deg - chunk);
    const int si = (lane < cnt) ? csr_src[beg + chunk + lane] : 0;
    int s = __shfl(si, 0);
    float4 xlv_next = ((const float4*)xl)[(size_t)s * 64 + lane];
    for (int j = 0; j < cnt; ++j) {
      const float4 xlv = xlv_next;
      if (j + 1 < cnt) {
        const int s2 = __shfl(si, j + 1);
        xlv_next = ((const float4*)xl)[(size_t)s2 * 64 + lane];
      }
      float p0 = lrelu(xlv.x + xrv.x) * attv.x;
      p0 = fmaf(lrelu(xlv.y + xrv.y), attv.y, p0);
      p0 = fmaf(lrelu(xlv.z + xrv.z), attv.z, p0);
      p0 = fmaf(lrelu(xlv.w + xrv.w), attv.w, p0);
      p0 += __shfl_xor(p0, 1);
      p0 += __shfl_xor(p0, 2);
      p0 += __shfl_xor(p0, 4);
      p0 += __shfl_xor(p0, 8);
      const float mnew = fmaxf(m, p0);
      const float scale = __expf(m - mnew);
      const float p = __expf(p0 - mnew);
      dsum = fmaf(dsum, scale, p);
      acc.x = fmaf(acc.x, scale, p * xlv.x);
      acc.y = fmaf(acc.y, scale, p * xlv.y);
      acc.z = fmaf(acc.z, scale, p * xlv.z);
      acc.w = fmaf(acc.w, scale, p * xlv.w);
      m = mnew;
    }
  }
  const float inv = (deg > 0) ? 1.0f / dsum : 0.f;
  const float4 b4 = ((const float4*)bias)[lane];
  float4 o;
  o.x = fmaf(acc.x, inv, b4.x); o.x = o.x > 0.f ? o.x : expm1f(o.x);
  o.y = fmaf(acc.y, inv, b4.y); o.y = o.y > 0.f ? o.y : expm1f(o.y);
  o.z = fmaf(acc.z, inv, b4.z); o.z = o.z > 0.f ? o.z : expm1f(o.z);
  o.w = fmaf(acc.w, inv, b4.w); o.w = o.w > 0.f ? o.w : expm1f(o.w);
  ((float4*)out)[(size_t)n * 64 + lane] = o;
}

// ---------------- layer 2 fused: 16-lane group per node + readout ----------------
__global__ __launch_bounds__(256) void node_l2_fused(
    const float* __restrict__ xl, const float* __restrict__ xr,
    const int* __restrict__ csr_src, const int* __restrict__ base,
    const float* __restrict__ att, const float* __restrict__ bias,
    const float* __restrict__ Wro, const float* __restrict__ bro,
    float* __restrict__ out, int N) {
  const int gl = threadIdx.x & 15;             // lane within group (4 channels each)
  const int n = blockIdx.x * 16 + (threadIdx.x >> 4);
  const int gbase = (threadIdx.x & 63) & 48;   // group's base lane within the wave
  if (n >= N) return;
  const int beg = base[n];
  const int deg = base[n + 1] - beg;
  const float4 xrv = ((const float4*)xr)[(size_t)n * 16 + gl];
  const float4 attv = ((const float4*)att)[gl];

  float m = -INFINITY, dsum = 0.f;
  float4 acc = make_float4(0.f, 0.f, 0.f, 0.f);

  for (int chunk = 0; chunk < deg; chunk += 16) {
    const int cnt = min(16, deg - chunk);
    const int si = (gl < cnt) ? csr_src[beg + chunk + gl] : 0;
    int s = __shfl(si, gbase);
    float4 xlv_next = ((const float4*)xl)[(size_t)s * 16 + gl];
    for (int j = 0; j < cnt; ++j) {
      const float4 xlv = xlv_next;
      if (j + 1 < cnt) {
        const int s2 = __shfl(si, gbase + j + 1);
        xlv_next = ((const float4*)xl)[(size_t)s2 * 16 + gl];
      }
      float p0 = lrelu(xlv.x + xrv.x) * attv.x;
      p0 = fmaf(lrelu(xlv.y + xrv.y), attv.y, p0);
      p0 = fmaf(lrelu(xlv.z + xrv.z), attv.z, p0);
      p0 = fmaf(lrelu(xlv.w + xrv.w), attv.w, p0);
      p0 += __shfl_xor(p0, 1);
      p0 += __shfl_xor(p0, 2);
      p0 += __shfl_xor(p0, 4);
      p0 += __shfl_xor(p0, 8);
      const float mnew = fmaxf(m, p0);
      const float scale = __expf(m - mnew);
      const float p = __expf(p0 - mnew);
      dsum = fmaf(dsum, scale, p);
      acc.x = fmaf(acc.x, scale, p * xlv.x);
      acc.y = fmaf(acc.y, scale, p * xlv.y);
      acc.z = fmaf(acc.z, scale, p * xlv.z);
      acc.w = fmaf(acc.w, scale, p * xlv.w);
      m = mnew;
    }
  }
  const float inv = (deg > 0) ? 1.0f / dsum : 0.f;
  const float4 b4 = ((const float4*)bias)[gl];
  float ox = fmaf(acc.x, inv, b4.x); ox = ox > 0.f ? ox : expm1f(ox);
  float oy = fmaf(acc.y, inv, b4.y); oy = oy > 0.f ? oy : expm1f(oy);
  float oz = fmaf(acc.z, inv, b4.z); oz = oz > 0.f ? oz : expm1f(oz);
  float ow = fmaf(acc.w, inv, b4.w); ow = ow > 0.f ? ow : expm1f(ow);
  const float4 w4 = ((const float4*)Wro)[gl];
  float r = ox * w4.x + oy * w4.y + oz * w4.z + ow * w4.w;
  r += __shfl_xor(r, 1);
  r += __shfl_xor(r, 2);
  r += __shfl_xor(r, 4);
  r += __shfl_xor(r, 8);
  if (gl == 0) out[n] = r + bro[0];
}

extern "C" void kernel_launch(void* const* d_in, const int* in_sizes, int n_in,
                              void* d_out, int out_size, void* d_ws, size_t ws_size,
                              hipStream_t stream) {
  const float* x     = (const float*)d_in[0];
  const int*   ei    = (const int*)d_in[1];
  const float* W1l   = (const float*)d_in[2];
  const float* b1l   = (const float*)d_in[3];
  const float* W1r   = (const float*)d_in[4];
  const float* b1r   = (const float*)d_in[5];
  const float* att1  = (const float*)d_in[6];
  const float* bias1 = (const float*)d_in[7];
  const float* W2l   = (const float*)d_in[8];
  const float* b2l   = (const float*)d_in[9];
  const float* W2r   = (const float*)d_in[10];
  const float* b2r   = (const float*)d_in[11];
  const float* att2  = (const float*)d_in[12];
  const float* bias2 = (const float*)d_in[13];
  const float* Wro   = (const float*)d_in[14];
  const float* bro   = (const float*)d_in[15];

  const int N = in_sizes[0] / 128;
  const int E = in_sizes[1] / 2;
  const int* src = ei;
  const int* dst = ei + E;

  // ---- workspace layout (floats) ----
  float* A    = (float*)d_ws;                 // xl1 [N*256]; later xl2/xr2 [N*64 each]
  float* B    = A + (size_t)N * 256;          // xr1 [N*256]
  float* Hbuf = B + (size_t)N * 256;          // h1 [N*256]
  int* csr_src = (int*)(Hbuf + (size_t)N * 256);  // [E]
  int* deg     = csr_src + E;                 // [N]
  int* base    = deg + N;                     // [N+1]
  int* cursor  = base + N + 1;                // [N]
  int* bsum    = cursor + N;                  // [256]
  int* boff    = bsum + 256;                  // [256]

  const int EB = (E + 255) / 256;
  const int NB = (N + 255) / 256;

  // ---- CSR build ----
  fill_u32<<<dim3(98), dim3(256), 0, stream>>>((unsigned*)deg, 0u, N);
  fill_u32<<<dim3(98), dim3(256), 0, stream>>>((unsigned*)cursor, 0u, N);
  hist_dst<<<dim3(EB), dim3(256), 0, stream>>>(dst, deg, E);
  scan1<<<dim3(NB), dim3(256), 0, stream>>>(deg, base, bsum, N);
  scan2<<<dim3(1), dim3(256), 0, stream>>>(bsum, boff, NB);
  scan3<<<dim3(NB + 1), dim3(256), 0, stream>>>(base, deg, boff, N, E);
  csr_build<<<dim3(EB), dim3(256), 0, stream>>>(src, dst, base, cursor, csr_src, E);

  // ---- layer 1 ----
  float* xl1 = A;
  float* xr1 = B;
  gemm_l1<<<dim3(N / 8), dim3(256), 0, stream>>>(x, W1l, b1l, xl1, N);
  gemm_l1<<<dim3(N / 8), dim3(256), 0, stream>>>(x, W1r, b1r, xr1, N);
  node_l1_fused<<<dim3((N + 3) / 4), dim3(256), 0, stream>>>(xl1, xr1, csr_src, base, att1,
                                                             bias1, Hbuf, N);

  // ---- layer 2 (xl1/xr1 dead) ----
  float* xl2 = A;
  float* xr2 = A + (size_t)N * 64;
  gemm_l2<<<dim3(N / 16), dim3(256), 0, stream>>>(Hbuf, W2l, b2l, xl2, N);
  gemm_l2<<<dim3(N / 16), dim3(256), 0, stream>>>(Hbuf, W2r, b2r, xr2, N);
  node_l2_fused<<<dim3((N + 15) / 16), dim3(256), 0, stream>>>(xl2, xr2, csr_src, base, att2,
                                                               bias2, Wro, bro, (float*)d_out, N);
}